// Round 5
// baseline (209.947 us; speedup 1.0000x reference)
//
#include <hip/hip_runtime.h>
#include <math.h>

#define NC 32
#define NSTEPS 32
#define NB 1024   // value buckets for locality binning

// ---------------------------------------------------------------------------
// K_pre: per-(theta,cell) coefficients (A = e^a, 32*B = 32*b*phi(a)).
// Identical arithmetic to rounds 0-3 (absmax canary depends on it).
// ---------------------------------------------------------------------------
__global__ void trels_kernel(const float* __restrict__ theta,
                             const float* __restrict__ basis,
                             float2* __restrict__ trels,
                             int n_theta, int d) {
    int i = blockIdx.x * blockDim.x + threadIdx.x;
    if (i >= n_theta * NC) return;
    int j = i / NC, c = i % NC;
    float a = 0.0f, b = 0.0f;
    for (int k = 0; k < d; ++k) {
        float t = theta[j * d + k];
        a = fmaf(basis[(2 * c) * d + k],     t, a);
        b = fmaf(basis[(2 * c + 1) * d + k], t, b);
    }
    const float dT = 1.0f / (float)NSTEPS;
    a *= dT; b *= dT;
    float A = expf(a);
    float phi = (fabsf(a) < 1e-6f) ? (1.0f + 0.5f * a) : (expm1f(a) / a);
    trels[i] = make_float2(A, 32.0f * (b * phi));
}

// ---------------------------------------------------------------------------
// K1: histogram of points into NB value buckets (theta-independent).
// ---------------------------------------------------------------------------
__global__ void hist_kernel(const float* __restrict__ pts,
                            unsigned* __restrict__ hist, int n) {
    __shared__ unsigned lh[NB];
    for (int b = threadIdx.x; b < NB; b += blockDim.x) lh[b] = 0;
    __syncthreads();
    for (int i = blockIdx.x * blockDim.x + threadIdx.x; i < n;
         i += gridDim.x * blockDim.x) {
        float x = pts[i];
        int b = (int)(x * (float)NB);
        b = b < 0 ? 0 : (b > NB - 1 ? NB - 1 : b);
        atomicAdd(&lh[b], 1u);
    }
    __syncthreads();
    for (int b = threadIdx.x; b < NB; b += blockDim.x)
        if (lh[b]) atomicAdd(&hist[b], lh[b]);
}

// ---------------------------------------------------------------------------
// K2: exclusive scan of hist (1 block, NB threads); hist becomes cursors.
// ---------------------------------------------------------------------------
__global__ void scan_kernel(unsigned* __restrict__ hist) {
    __shared__ unsigned s0[NB], s1[NB];
    int t = threadIdx.x;
    unsigned v = hist[t];
    s0[t] = v;
    __syncthreads();
    unsigned* src = s0; unsigned* dst = s1;
    for (int off = 1; off < NB; off <<= 1) {
        unsigned x = src[t];
        if (t >= off) x += src[t - off];
        dst[t] = x;
        __syncthreads();
        unsigned* tmp = src; src = dst; dst = tmp;
    }
    hist[t] = src[t] - v;   // exclusive prefix -> scatter cursor
}

// ---------------------------------------------------------------------------
// K3: scatter points into binned order; record inverse permutation.
// ---------------------------------------------------------------------------
__global__ void scatter_kernel(const float* __restrict__ pts,
                               unsigned* __restrict__ cursor,
                               float* __restrict__ bx,
                               unsigned* __restrict__ inv, int n) {
    int i = blockIdx.x * blockDim.x + threadIdx.x;
    if (i >= n) return;
    float x = pts[i];
    int b = (int)(x * (float)NB);
    b = b < 0 ? 0 : (b > NB - 1 ? NB - 1 : b);
    unsigned p = atomicAdd(&cursor[b], 1u);
    bx[p] = x;
    inv[i] = p;
}

// ---------------------------------------------------------------------------
// K4: main integration. One wave = 512 value-adjacent points for one theta.
// Bracket [ylo,yhi] is tracked through a SOUND fp32 recurrence:
//   uniform step (cell(ylo)==cell(yhi)): all points provably share the cell
//     (floor/clamp monotone), one broadcast ds_read_b64, 1 fma/point —
//     bit-exact vs the per-point reference recurrence.
//   straddling step: exact per-point cell + gather (R3 path), and the
//     bracket is updated with min/max over ALL cells in [clo,chi]:
//       ylo' = min_c fmaf(A_c, ylo, B_c),  yhi' = max_c fmaf(A_c, yhi, B_c)
//     which is a rigorous bound because each fmaf is monotone in y (A>0,
//     RN rounding monotone) — this fixes R4's bracket-escape bug.
// ---------------------------------------------------------------------------
__global__ void __launch_bounds__(256)
main_kernel(const float* __restrict__ bx, const float2* __restrict__ trels,
            float* __restrict__ obin, int n_points) {
    __shared__ float2 tab[NC];          // (A, 32*B) for this block's theta

    const int lane = threadIdx.x & 63;
    const int wid  = threadIdx.x >> 6;
    const int chunks = n_points >> 9;   // 512-point chunks per theta
    const int gw = blockIdx.x * 4 + wid;
    const int j = gw / chunks;          // uniform across block (chunks%4==0)
    const int chunk = gw % chunks;
    const int base = (chunk << 9) + lane * 8;

    if (threadIdx.x < NC)
        tab[threadIdx.x] = trels[j * NC + threadIdx.x];
    __syncthreads();

    float y[8];
    {
        float4 v0 = *(const float4*)(bx + base);
        float4 v1 = *(const float4*)(bx + base + 4);
        y[0] = v0.x * 32.0f; y[1] = v0.y * 32.0f;   // exact 2^5 scale
        y[2] = v0.z * 32.0f; y[3] = v0.w * 32.0f;
        y[4] = v1.x * 32.0f; y[5] = v1.y * 32.0f;
        y[6] = v1.z * 32.0f; y[7] = v1.w * 32.0f;
    }

    float ylo = y[0], yhi = y[0];
#pragma unroll
    for (int i = 1; i < 8; ++i) {
        ylo = fminf(ylo, y[i]); yhi = fmaxf(yhi, y[i]);
    }
#pragma unroll
    for (int off = 32; off; off >>= 1) {
        ylo = fminf(ylo, __shfl_xor(ylo, off, 64));
        yhi = fmaxf(yhi, __shfl_xor(yhi, off, 64));
    }
    // all lanes now hold identical ylo/yhi -> branches are wave-uniform

    for (int s = 0; s < NSTEPS; ++s) {
        float cflo = fminf(fmaxf(floorf(ylo), 0.0f), 31.0f);
        float cfhi = fminf(fmaxf(floorf(yhi), 0.0f), 31.0f);
        if (cflo == cfhi) {
            float2 t = tab[(int)cflo];  // uniform addr -> LDS broadcast
#pragma unroll
            for (int i = 0; i < 8; ++i) y[i] = fmaf(t.x, y[i], t.y);
            ylo = fmaf(t.x, ylo, t.y);
            yhi = fmaf(t.x, yhi, t.y);
        } else {
            int clo = (int)cflo, chi = (int)cfhi;
#pragma unroll
            for (int i = 0; i < 8; ++i) {
                float cf = fminf(fmaxf(floorf(y[i]), 0.0f), 31.0f);
                float2 t = tab[(int)cf];
                y[i] = fmaf(t.x, y[i], t.y);
            }
            float nlo = 3.0e38f, nhi = -3.0e38f;
            for (int c = clo; c <= chi; ++c) {
                float2 t = tab[c];
                nlo = fminf(nlo, fmaf(t.x, ylo, t.y));
                nhi = fmaxf(nhi, fmaf(t.x, yhi, t.y));
            }
            ylo = nlo; yhi = nhi;
        }
    }

    const float inv32 = 1.0f / 32.0f;
    float* op = obin + j * n_points + base;
    float4 o0 = make_float4(y[0]*inv32, y[1]*inv32, y[2]*inv32, y[3]*inv32);
    float4 o1 = make_float4(y[4]*inv32, y[5]*inv32, y[6]*inv32, y[7]*inv32);
    *(float4*)op       = o0;
    *(float4*)(op + 4) = o1;
}

// ---------------------------------------------------------------------------
// K5: unpermute binned results to original order (coalesced writes; random
// reads served by L2/L3 on an 8 MB working set).
// ---------------------------------------------------------------------------
__global__ void unperm_kernel(const float* __restrict__ obin,
                              const unsigned* __restrict__ inv,
                              float* __restrict__ out,
                              int n_points, int n_theta) {
    int i = blockIdx.x * blockDim.x + threadIdx.x;
    if (i >= n_points) return;
    unsigned p = inv[i];
    for (int t = 0; t < n_theta; ++t)
        out[t * n_points + i] = obin[t * n_points + p];
}

extern "C" void kernel_launch(void* const* d_in, const int* in_sizes, int n_in,
                              void* d_out, int out_size, void* d_ws, size_t ws_size,
                              hipStream_t stream) {
    const float* points = (const float*)d_in[0];  // [1, n_points]
    const float* theta  = (const float*)d_in[1];  // [n_theta, d]
    const float* basis  = (const float*)d_in[2];  // [2*NC, d]

    int n_points = in_sizes[0];
    int d        = in_sizes[2] / (2 * NC);        // 30
    int n_theta  = in_sizes[1] / d;               // 8

    // ws layout (n_points = 256K -> offsets all 16B-aligned):
    char* ws = (char*)d_ws;
    float*    bx    = (float*)ws;                                  // 1 MB
    unsigned* invp  = (unsigned*)(ws + (size_t)n_points * 4);      // 1 MB
    unsigned* hist  = (unsigned*)(ws + (size_t)n_points * 8);      // 4 KB
    float2*   trels = (float2*)(ws + (size_t)n_points * 8 + 8192); // 2 KB
    float*    obin  = (float*)(ws + (size_t)n_points * 8 + 16384); // 8 MB

    hipMemsetAsync(hist, 0, NB * sizeof(unsigned), stream);
    trels_kernel<<<1, 256, 0, stream>>>(theta, basis, trels, n_theta, d);
    hist_kernel<<<256, 256, 0, stream>>>(points, hist, n_points);
    scan_kernel<<<1, NB, 0, stream>>>(hist);
    scatter_kernel<<<(n_points + 255) / 256, 256, 0, stream>>>(
        points, hist, bx, invp, n_points);

    int chunks = n_points >> 9;                   // 512
    main_kernel<<<n_theta * chunks / 4, 256, 0, stream>>>(
        bx, trels, obin, n_points);

    unperm_kernel<<<(n_points + 255) / 256, 256, 0, stream>>>(
        obin, invp, (float*)d_out, n_points, n_theta);
}

// Round 6
// 69.063 us; speedup vs baseline: 3.0399x; 3.0399x over previous
//
#include <hip/hip_runtime.h>
#include <math.h>

#define NC 32
#define NSTEPS 32

constexpr int BLOCK = 256;
constexpr int PTS = 4;                 // 4 chains/thread; 32 waves/CU TLP
constexpr int CHUNK = BLOCK * PTS;     // 1024 points per block

// Fused kernel, per-step body minimized to 4 VALU + 1 DS:
//   state z = 256*x (2^8 scale: exact in fp32, commutes with RN rounding)
//   cell byte-address = (int)med3(z, 0, 255.5) & ~7
//     - med3 clamps (fminf(fmaxf)) -> v_med3_f32
//     - (int) = v_cvt_i32_f32 (trunc == floor for z>=0)
//     - & ~7 turns trunc(z) into 8*floor(z/8) = byte offset of float2 tab[cell]
//     - clamp bound 255.5: z in (255.5,256) still maps to cell 31 (correct),
//       z >= 256 clamps to cell 31, z < 0 clamps to cell 0 (matches jnp.clip)
//   z' = fmaf(A, z, 256*b*phi)  == 256 * fmaf(A, x, b*phi) bitwise
// Table (A, 256*B) in LDS; random gathers merge same-address lanes
// (<=2 distinct dword addrs per bank -> free 2-way case).
__global__ void __launch_bounds__(BLOCK)
cpab_kernel(const float* __restrict__ points,
            const float* __restrict__ theta,
            const float* __restrict__ basis,
            float* __restrict__ out,
            int n_points, int d) {
    __shared__ float2 tab[NC];         // (A, 256*B)

    const int blocks_per_theta = n_points / CHUNK;   // 256
    const int j = blockIdx.x / blocks_per_theta;
    const int tid = threadIdx.x;

    if (tid < NC) {
        const int c = tid;
        const float* __restrict__ th = theta + j * d;
        const float* __restrict__ ba = basis + (2 * c) * d;
        const float* __restrict__ bb = basis + (2 * c + 1) * d;
        float a = 0.0f, b = 0.0f;
#pragma unroll 6
        for (int k = 0; k < d; ++k) {
            float t = th[k];
            a = fmaf(ba[k], t, a);
            b = fmaf(bb[k], t, b);
        }
        const float dT = 1.0f / (float)NSTEPS;
        a *= dT;
        b *= dT;
        float A = expf(a);
        // phi(a) = (e^a - 1)/a, stable small-a branch (matches reference)
        float phi = (fabsf(a) < 1e-6f) ? (1.0f + 0.5f * a) : (expm1f(a) / a);
        tab[c] = make_float2(A, 256.0f * (b * phi));  // exact 2^8 scale of B
    }
    __syncthreads();

    const int base = (blockIdx.x % blocks_per_theta) * CHUNK + tid * PTS;

    float z[PTS];
    {
        float4 v = *(const float4*)(points + base);
        z[0] = v.x * 256.0f; z[1] = v.y * 256.0f;    // exact 2^8 scale
        z[2] = v.z * 256.0f; z[3] = v.w * 256.0f;
    }

    const char* tb = (const char*)tab;
#pragma unroll
    for (int s = 0; s < NSTEPS; ++s) {
#pragma unroll
        for (int i = 0; i < PTS; ++i) {
            float zc = fminf(fmaxf(z[i], 0.0f), 255.5f);  // v_med3_f32
            int addr = ((int)zc) & ~7;                    // v_cvt + v_and
            float2 t = *(const float2*)(tb + addr);       // ds_read_b64
            z[i] = fmaf(t.x, z[i], t.y);                  // v_fma_f32
        }
    }

    const float inv = 1.0f / 256.0f;                 // exact scale back
    float4 o = make_float4(z[0] * inv, z[1] * inv, z[2] * inv, z[3] * inv);
    *(float4*)(out + j * n_points + base) = o;
}

extern "C" void kernel_launch(void* const* d_in, const int* in_sizes, int n_in,
                              void* d_out, int out_size, void* d_ws, size_t ws_size,
                              hipStream_t stream) {
    const float* points = (const float*)d_in[0];  // [1, n_points]
    const float* theta  = (const float*)d_in[1];  // [n_theta, d]
    const float* basis  = (const float*)d_in[2];  // [2*NC, d]

    int n_points = in_sizes[0];
    int d        = in_sizes[2] / (2 * NC);        // 30
    int n_theta  = in_sizes[1] / d;               // 8

    int grid = n_theta * (n_points / CHUNK);      // 8 * 256 = 2048 blocks
    cpab_kernel<<<grid, BLOCK, 0, stream>>>(points, theta, basis,
                                            (float*)d_out, n_points, d);
}